// Round 1
// baseline (838.920 us; speedup 1.0000x reference)
//
#include <hip/hip_runtime.h>

// QuantMHSANet: Brevitas-style per-tensor fake-quant MHSA.
// S=2048 B=4 E=512 H=8 D=64. All GEMMs run as integer-exact bf16 MFMA.
constexpr int cS = 2048, cB = 4, cE = 512, cH = 8, cD = 64;
constexpr int cSB = cS * cB;   // 8192 rows
constexpr int cBH = cB * cH;   // 32 (b,h) pairs
constexpr int cN  = cSB * cE;  // 4194304 elements

typedef __bf16 v8bf  __attribute__((ext_vector_type(8)));
typedef float  f32x4 __attribute__((ext_vector_type(4)));

// ---- stat slots (float) ----
// 0 amax_x | 1..4 amax_w(q,k,v,o) | 5 amax_q 6 amax_k 7 amax_v | 8 max_invz
// 9 amax_ctx | 10 amax_y | 11 s0 | 12 s_in | 13..16 s_w(q,k,v,o) |
// 17 s_q 18 s_k 19 s_v | 20 scale_a 21 inv_scale_a 22 ctx_scale | 23 s_c | 24 s_y | 25 s_q*s_k

__device__ __forceinline__ unsigned short f2bf(float f) {
  unsigned u = __float_as_uint(f);                 // RNE f32->bf16 (exact for our ints)
  return (unsigned short)((u + 0x7FFFu + ((u >> 16) & 1u)) >> 16);
}
__device__ __forceinline__ float clip8(float t) { return fminf(fmaxf(t, -128.f), 127.f); }
__device__ __forceinline__ float wave_max(float v) {
#pragma unroll
  for (int o = 32; o > 0; o >>= 1) v = fmaxf(v, __shfl_down(v, o));
  return v;
}

// ---------------- reductions & scales ----------------
__global__ void absmax_kernel(const float* __restrict__ p, int n4, unsigned* slot) {
  int tid = blockIdx.x * blockDim.x + threadIdx.x, stride = gridDim.x * blockDim.x;
  float m = 0.f;
  for (int i = tid; i < n4; i += stride) {
    float4 v = ((const float4*)p)[i];
    m = fmaxf(m, fmaxf(fmaxf(fabsf(v.x), fabsf(v.y)), fmaxf(fabsf(v.z), fabsf(v.w))));
  }
  m = wave_max(m);
  __shared__ float sm[4];
  int lane = threadIdx.x & 63, wid = threadIdx.x >> 6;
  if (lane == 0) sm[wid] = m;
  __syncthreads();
  if (threadIdx.x == 0) {
    float mm = sm[0];
    for (int w = 1; w < (int)blockDim.x / 64; ++w) mm = fmaxf(mm, sm[w]);
    atomicMax(slot, __float_as_uint(mm));
  }
}

__global__ void scales_kernel(float* st, int stage) {
  if (stage == 0) {
    float s0 = fmaxf(st[0], 1e-8f) / 127.f;
    st[11] = s0;
    float mxq = s0 * 127.f;                 // max|xq| (max int is always 127)
    st[12] = fmaxf(mxq, 1e-8f) / 127.f;     // s_in
    for (int i = 0; i < 4; ++i) st[13 + i] = fmaxf(st[1 + i], 1e-8f) / 127.f;
  } else if (stage == 1) {
    st[17] = fmaxf(st[5] * 0.125f, 1e-8f) / 127.f;  // s_q (q/sqrt(64))
    st[18] = fmaxf(st[6], 1e-8f) / 127.f;           // s_k
    st[19] = fmaxf(st[7], 1e-8f) / 127.f;           // s_v
    st[25] = st[17] * st[18];
  } else if (stage == 2) {
    float sa = fmaxf(st[8], 1e-8f) / 255.f;         // max(attn)=1/minZ
    st[20] = sa; st[21] = 1.f / sa; st[22] = sa * st[19];
  } else if (stage == 3) {
    st[23] = fmaxf(st[9], 1e-8f) / 127.f;           // s_c
  } else {
    st[24] = fmaxf(st[10], 1e-8f) / 127.f;          // s_y
  }
}

// ---------------- elementwise quantizers ----------------
__global__ void quant_x_kernel(const float* __restrict__ x, unsigned short* __restrict__ xq,
                               const float* st, int n4) {
  float s0 = st[11], si = st[12];
  int tid = blockIdx.x * blockDim.x + threadIdx.x, stride = gridDim.x * blockDim.x;
  for (int i = tid; i < n4; i += stride) {
    float4 v = ((const float4*)x)[i];
    ushort4 o; float t;
    t = s0 * clip8(rintf(v.x / s0)); o.x = f2bf(clip8(rintf(t / si)));
    t = s0 * clip8(rintf(v.y / s0)); o.y = f2bf(clip8(rintf(t / si)));
    t = s0 * clip8(rintf(v.z / s0)); o.z = f2bf(clip8(rintf(t / si)));
    t = s0 * clip8(rintf(v.w / s0)); o.w = f2bf(clip8(rintf(t / si)));
    ((ushort4*)xq)[i] = o;
  }
}

__global__ void quant_s8_kernel(const float* __restrict__ in, unsigned short* __restrict__ outp,
                                int n4, const float* st, int slot, float premul) {
  float s = st[slot];
  int tid = blockIdx.x * blockDim.x + threadIdx.x, stride = gridDim.x * blockDim.x;
  for (int i = tid; i < n4; i += stride) {
    float4 v = ((const float4*)in)[i];
    ushort4 o;
    o.x = f2bf(clip8(rintf(v.x * premul / s)));
    o.y = f2bf(clip8(rintf(v.y * premul / s)));
    o.z = f2bf(clip8(rintf(v.z * premul / s)));
    o.w = f2bf(clip8(rintf(v.w * premul / s)));
    ((ushort4*)outp)[i] = o;
  }
}

__global__ void bias_kernel(const float* __restrict__ bsrc, float* __restrict__ bdst,
                            const float* st, int slot_in, int slot_w) {
  int f = blockIdx.x * blockDim.x + threadIdx.x;
  if (f < cE) {
    float s = st[slot_in] * st[slot_w];
    bdst[f] = s * rintf(bsrc[f] / s);   // int32 clip is a no-op at these magnitudes
  }
}

// V: [BH][S][D] f32 -> quantized, transposed [BH][D][S] bf16 (K-major for PV B-frags)
__global__ __launch_bounds__(256) void quant_vT_kernel(const float* __restrict__ v,
                                                       unsigned short* __restrict__ vT,
                                                       const float* st) {
  __shared__ unsigned short tile[64][65];
  int bh = blockIdx.y, s0 = blockIdx.x * 64;
  float sv = st[19];
  int td = threadIdx.x & 63, tr = threadIdx.x >> 6;
  for (int r = tr; r < 64; r += 4)
    tile[r][td] = f2bf(clip8(rintf(v[((size_t)bh * cS + s0 + r) * cD + td] / sv)));
  __syncthreads();
  for (int r = tr; r < 64; r += 4)
    vT[((size_t)bh * cD + r) * cS + s0 + td] = tile[td][r];
}

__global__ void final_quant_kernel(float* __restrict__ y, const float* st, int n4) {
  float s = st[24];
  int tid = blockIdx.x * blockDim.x + threadIdx.x, stride = gridDim.x * blockDim.x;
  for (int i = tid; i < n4; i += stride) {
    float4 v = ((float4*)y)[i];
    v.x = s * clip8(rintf(v.x / s)); v.y = s * clip8(rintf(v.y / s));
    v.z = s * clip8(rintf(v.z / s)); v.w = s * clip8(rintf(v.w / s));
    ((float4*)y)[i] = v;
  }
}

// ---------------- integer-exact bf16 MFMA GEMM ----------------
// C[row,col] = sum_e A[row][e]*W[col][e]; both stored K-major (512 cols bf16-int).
// OUTMODE 0: write [B][H][S][D] (heads split) ; OUTMODE 1: write row-major [SB][E].
template <int OUTMODE>
__global__ __launch_bounds__(256) void gemm_kernel(const unsigned short* __restrict__ A,
                                                   const unsigned short* __restrict__ Wb,
                                                   const float* __restrict__ bias,
                                                   float* __restrict__ out, const float* st,
                                                   int slot_in, int slot_w, unsigned* amax_slot) {
  int wid = threadIdx.x >> 6, lane = threadIdx.x & 63;
  int wm = wid >> 1, wn = wid & 1;
  int row0 = blockIdx.x * 64 + wm * 32;
  int col0 = blockIdx.y * 64 + wn * 32;
  int lr = lane & 15, lk = (lane >> 4) * 8;
  f32x4 acc[2][2] = {};
  const unsigned short* a0p = A + (size_t)(row0 + lr) * cE + lk;
  const unsigned short* a1p = A + (size_t)(row0 + 16 + lr) * cE + lk;
  const unsigned short* b0p = Wb + (size_t)(col0 + lr) * cE + lk;
  const unsigned short* b1p = Wb + (size_t)(col0 + 16 + lr) * cE + lk;
  for (int e0 = 0; e0 < cE; e0 += 32) {
    v8bf a0 = *(const v8bf*)(a0p + e0), a1 = *(const v8bf*)(a1p + e0);
    v8bf b0 = *(const v8bf*)(b0p + e0), b1 = *(const v8bf*)(b1p + e0);
    acc[0][0] = __builtin_amdgcn_mfma_f32_16x16x32_bf16(a0, b0, acc[0][0], 0, 0, 0);
    acc[0][1] = __builtin_amdgcn_mfma_f32_16x16x32_bf16(a0, b1, acc[0][1], 0, 0, 0);
    acc[1][0] = __builtin_amdgcn_mfma_f32_16x16x32_bf16(a1, b0, acc[1][0], 0, 0, 0);
    acc[1][1] = __builtin_amdgcn_mfma_f32_16x16x32_bf16(a1, b1, acc[1][1], 0, 0, 0);
  }
  float scale = st[slot_in] * st[slot_w];
  float lmax = 0.f;
#pragma unroll
  for (int mi = 0; mi < 2; ++mi)
#pragma unroll
    for (int ni = 0; ni < 2; ++ni)
#pragma unroll
      for (int r = 0; r < 4; ++r) {
        int row = row0 + mi * 16 + (lane >> 4) * 4 + r;   // C/D: row=(l>>4)*4+reg
        int col = col0 + ni * 16 + lr;                    //      col=l&15
        float val = scale * acc[mi][ni][r] + bias[col];
        lmax = fmaxf(lmax, fabsf(val));
        if (OUTMODE == 0) {
          int s = row >> 2, bb = row & 3, h = col >> 6, d = col & 63;
          out[(((size_t)(bb * cH + h)) * cS + s) * cD + d] = val;
        } else {
          out[(size_t)row * cE + col] = val;
        }
      }
  lmax = wave_max(lmax);
  if (lane == 0) atomicMax(amax_slot, __float_as_uint(lmax));
}

// ---------------- attention pass 1: per-row (m, 1/Z), global max(1/Z) ----------------
__global__ __launch_bounds__(256) void attn_pass1_kernel(const unsigned short* __restrict__ qs,
                                                         const unsigned short* __restrict__ ks,
                                                         float* __restrict__ marr,
                                                         float* __restrict__ izarr,
                                                         const float* st, unsigned* maxiz_slot) {
  int bh = blockIdx.y;
  int wid = threadIdx.x >> 6, lane = threadIdx.x & 63;
  int lr = lane & 15, lk = (lane >> 4) * 8;
  int r0 = blockIdx.x * 64 + wid * 16;
  float sscale = st[25];
  v8bf aq0 = *(const v8bf*)(qs + ((size_t)bh * cS + r0 + lr) * cD + lk);
  v8bf aq1 = *(const v8bf*)(qs + ((size_t)bh * cS + r0 + lr) * cD + 32 + lk);
  float mrun[4] = {-1e30f, -1e30f, -1e30f, -1e30f};
  float zsum[4] = {0.f, 0.f, 0.f, 0.f};
  for (int kt = 0; kt < cS; kt += 64) {
    f32x4 sc[4];
#pragma unroll
    for (int jc = 0; jc < 4; ++jc) {
      const unsigned short* kb = ks + ((size_t)bh * cS + kt + jc * 16 + lr) * cD + lk;
      v8bf b0 = *(const v8bf*)kb, b1 = *(const v8bf*)(kb + 32);
      f32x4 z = {0.f, 0.f, 0.f, 0.f};
      z = __builtin_amdgcn_mfma_f32_16x16x32_bf16(aq0, b0, z, 0, 0, 0);
      z = __builtin_amdgcn_mfma_f32_16x16x32_bf16(aq1, b1, z, 0, 0, 0);
      sc[jc] = z;
    }
#pragma unroll
    for (int r = 0; r < 4; ++r) {
      float s0v = sscale * sc[0][r], s1v = sscale * sc[1][r];
      float s2v = sscale * sc[2][r], s3v = sscale * sc[3][r];
      float tm = fmaxf(fmaxf(s0v, s1v), fmaxf(s2v, s3v));
      for (int o = 1; o < 16; o <<= 1) tm = fmaxf(tm, __shfl_xor(tm, o));
      float nm = fmaxf(mrun[r], tm);
      float ps = expf(s0v - nm) + expf(s1v - nm) + expf(s2v - nm) + expf(s3v - nm);
      for (int o = 1; o < 16; o <<= 1) ps += __shfl_xor(ps, o);
      zsum[r] = zsum[r] * expf(mrun[r] - nm) + ps;
      mrun[r] = nm;
    }
  }
  float wmax = 0.f;
  if (lr == 0) {
#pragma unroll
    for (int r = 0; r < 4; ++r) {
      int row = r0 + (lane >> 4) * 4 + r;
      float iz = 1.0f / zsum[r];
      marr[bh * cS + row] = mrun[r];
      izarr[bh * cS + row] = iz;
      wmax = fmaxf(wmax, iz);
    }
  }
  wmax = wave_max(wmax);
  if (lane == 0) atomicMax(maxiz_slot, __float_as_uint(wmax));
}

// ---------------- attention pass 2: P=u8-quant(softmax) ; ctx += P*V ----------------
__global__ __launch_bounds__(256) void attn_pass2_kernel(
    const unsigned short* __restrict__ qs, const unsigned short* __restrict__ ks,
    const unsigned short* __restrict__ vT, const float* __restrict__ marr,
    const float* __restrict__ izarr, float* __restrict__ ctx, const float* st,
    unsigned* amax_slot) {
  __shared__ __align__(16) unsigned short plds[4][16][72];  // per-wave P tile, padded
  int bh = blockIdx.y, b = bh >> 3, h = bh & 7;
  int wid = threadIdx.x >> 6, lane = threadIdx.x & 63;
  int lr = lane & 15, lk = (lane >> 4) * 8;
  int r0 = blockIdx.x * 64 + wid * 16;
  float sscale = st[25], isa = st[21], cscale = st[22];
  v8bf aq0 = *(const v8bf*)(qs + ((size_t)bh * cS + r0 + lr) * cD + lk);
  v8bf aq1 = *(const v8bf*)(qs + ((size_t)bh * cS + r0 + lr) * cD + 32 + lk);
  float mr[4], izr[4];
  int rowbase = bh * cS + r0 + (lane >> 4) * 4;
#pragma unroll
  for (int r = 0; r < 4; ++r) { mr[r] = marr[rowbase + r]; izr[r] = izarr[rowbase + r]; }
  f32x4 cacc[4] = {};
  for (int kt = 0; kt < cS; kt += 64) {
    f32x4 sc[4];
#pragma unroll
    for (int jc = 0; jc < 4; ++jc) {
      const unsigned short* kb = ks + ((size_t)bh * cS + kt + jc * 16 + lr) * cD + lk;
      v8bf b0 = *(const v8bf*)kb, b1 = *(const v8bf*)(kb + 32);
      f32x4 z = {0.f, 0.f, 0.f, 0.f};
      z = __builtin_amdgcn_mfma_f32_16x16x32_bf16(aq0, b0, z, 0, 0, 0);
      z = __builtin_amdgcn_mfma_f32_16x16x32_bf16(aq1, b1, z, 0, 0, 0);
      sc[jc] = z;
    }
#pragma unroll
    for (int jc = 0; jc < 4; ++jc)
#pragma unroll
      for (int r = 0; r < 4; ++r) {
        float p = expf(sscale * sc[jc][r] - mr[r]) * izr[r];
        float a = fminf(fmaxf(rintf(p * isa), 0.f), 255.f);
        plds[wid][(lane >> 4) * 4 + r][jc * 16 + lr] = f2bf(a);
      }
    __syncthreads();
    v8bf ap0 = *(const v8bf*)&plds[wid][lr][lk];
    v8bf ap1 = *(const v8bf*)&plds[wid][lr][32 + lk];
#pragma unroll
    for (int dt = 0; dt < 4; ++dt) {
      const unsigned short* vb = vT + ((size_t)bh * cD + dt * 16 + lr) * cS + kt + lk;
      v8bf bv0 = *(const v8bf*)vb, bv1 = *(const v8bf*)(vb + 32);
      cacc[dt] = __builtin_amdgcn_mfma_f32_16x16x32_bf16(ap0, bv0, cacc[dt], 0, 0, 0);
      cacc[dt] = __builtin_amdgcn_mfma_f32_16x16x32_bf16(ap1, bv1, cacc[dt], 0, 0, 0);
    }
    __syncthreads();
  }
  float lmax = 0.f;
#pragma unroll
  for (int dt = 0; dt < 4; ++dt)
#pragma unroll
    for (int r = 0; r < 4; ++r) {
      int qrow = r0 + (lane >> 4) * 4 + r;
      int d = dt * 16 + lr;
      float val = cscale * cacc[dt][r];
      lmax = fmaxf(lmax, fabsf(val));
      ctx[((size_t)qrow * cB + b) * cE + h * cD + d] = val;  // [S][B][E]
    }
  lmax = wave_max(lmax);
  if (lane == 0) atomicMax(amax_slot, __float_as_uint(lmax));
}

// ---------------- launcher ----------------
extern "C" void kernel_launch(void* const* d_in, const int* in_sizes, int n_in, void* d_out,
                              int out_size, void* d_ws, size_t ws_size, hipStream_t stream) {
  (void)in_sizes; (void)n_in; (void)out_size; (void)ws_size;
  const float* x  = (const float*)d_in[0];
  const float* Wq = (const float*)d_in[1];
  const float* Wk = (const float*)d_in[2];
  const float* Wv = (const float*)d_in[3];
  const float* bq = (const float*)d_in[4];
  const float* bk = (const float*)d_in[5];
  const float* bv = (const float*)d_in[6];
  const float* Wo = (const float*)d_in[7];
  const float* bo = (const float*)d_in[8];
  float* out = (float*)d_out;

  char* ws = (char*)d_ws;
  size_t off = 0;
  auto alloc = [&](size_t bytes) { size_t o = off; off += (bytes + 255) & ~(size_t)255; return o; };
  float* st = (float*)(ws + alloc(64 * 4));
  unsigned short* xq  = (unsigned short*)(ws + alloc((size_t)cN * 2));
  unsigned short* wbq = (unsigned short*)(ws + alloc((size_t)cE * cE * 2));
  unsigned short* wbk = (unsigned short*)(ws + alloc((size_t)cE * cE * 2));
  unsigned short* wbv = (unsigned short*)(ws + alloc((size_t)cE * cE * 2));
  unsigned short* wbo = (unsigned short*)(ws + alloc((size_t)cE * cE * 2));
  float* bfq = (float*)(ws + alloc(cE * 4));
  float* bfk = (float*)(ws + alloc(cE * 4));
  float* bfv = (float*)(ws + alloc(cE * 4));
  float* bfo = (float*)(ws + alloc(cE * 4));
  float* qf = (float*)(ws + alloc((size_t)cN * 4));   // [BH][S][D]
  float* kf = (float*)(ws + alloc((size_t)cN * 4));
  float* vf = (float*)(ws + alloc((size_t)cN * 4));
  unsigned short* qsb = (unsigned short*)(ws + alloc((size_t)cN * 2));
  unsigned short* ksb = (unsigned short*)(ws + alloc((size_t)cN * 2));
  unsigned short* vTb = (unsigned short*)(ws + alloc((size_t)cN * 2));
  float* marr  = (float*)(ws + alloc((size_t)cBH * cS * 4));
  float* izarr = (float*)(ws + alloc((size_t)cBH * cS * 4));
  float* ctxf = qf;                      // alias: qf dead after quant(q)
  unsigned short* cib = (unsigned short*)kf;  // alias: kf dead after quant(k)
  // total ws ~ 87 MB

  int n4 = cN / 4;
  hipMemsetAsync(st, 0, 256, stream);
  absmax_kernel<<<1024, 256, 0, stream>>>(x, n4, (unsigned*)(st + 0));
  absmax_kernel<<<256, 256, 0, stream>>>(Wq, cE * cE / 4, (unsigned*)(st + 1));
  absmax_kernel<<<256, 256, 0, stream>>>(Wk, cE * cE / 4, (unsigned*)(st + 2));
  absmax_kernel<<<256, 256, 0, stream>>>(Wv, cE * cE / 4, (unsigned*)(st + 3));
  absmax_kernel<<<256, 256, 0, stream>>>(Wo, cE * cE / 4, (unsigned*)(st + 4));
  scales_kernel<<<1, 1, 0, stream>>>(st, 0);
  quant_x_kernel<<<1024, 256, 0, stream>>>(x, xq, st, n4);
  quant_s8_kernel<<<256, 256, 0, stream>>>(Wq, wbq, cE * cE / 4, st, 13, 1.0f);
  quant_s8_kernel<<<256, 256, 0, stream>>>(Wk, wbk, cE * cE / 4, st, 14, 1.0f);
  quant_s8_kernel<<<256, 256, 0, stream>>>(Wv, wbv, cE * cE / 4, st, 15, 1.0f);
  quant_s8_kernel<<<256, 256, 0, stream>>>(Wo, wbo, cE * cE / 4, st, 16, 1.0f);
  bias_kernel<<<2, 256, 0, stream>>>(bq, bfq, st, 12, 13);
  bias_kernel<<<2, 256, 0, stream>>>(bk, bfk, st, 12, 14);
  bias_kernel<<<2, 256, 0, stream>>>(bv, bfv, st, 12, 15);
  gemm_kernel<0><<<dim3(cSB / 64, cE / 64), 256, 0, stream>>>(xq, wbq, bfq, qf, st, 12, 13, (unsigned*)(st + 5));
  gemm_kernel<0><<<dim3(cSB / 64, cE / 64), 256, 0, stream>>>(xq, wbk, bfk, kf, st, 12, 14, (unsigned*)(st + 6));
  gemm_kernel<0><<<dim3(cSB / 64, cE / 64), 256, 0, stream>>>(xq, wbv, bfv, vf, st, 12, 15, (unsigned*)(st + 7));
  scales_kernel<<<1, 1, 0, stream>>>(st, 1);
  quant_s8_kernel<<<1024, 256, 0, stream>>>(qf, qsb, n4, st, 17, 0.125f);
  quant_s8_kernel<<<1024, 256, 0, stream>>>(kf, ksb, n4, st, 18, 1.0f);
  quant_vT_kernel<<<dim3(cS / 64, cBH), 256, 0, stream>>>(vf, vTb, st);
  attn_pass1_kernel<<<dim3(cS / 64, cBH), 256, 0, stream>>>(qsb, ksb, marr, izarr, st, (unsigned*)(st + 8));
  scales_kernel<<<1, 1, 0, stream>>>(st, 2);
  attn_pass2_kernel<<<dim3(cS / 64, cBH), 256, 0, stream>>>(qsb, ksb, vTb, marr, izarr, ctxf, st, (unsigned*)(st + 9));
  scales_kernel<<<1, 1, 0, stream>>>(st, 3);
  quant_s8_kernel<<<1024, 256, 0, stream>>>(ctxf, cib, n4, st, 23, 1.0f);
  bias_kernel<<<2, 256, 0, stream>>>(bo, bfo, st, 23, 16);
  gemm_kernel<1><<<dim3(cSB / 64, cE / 64), 256, 0, stream>>>(cib, wbo, bfo, out, st, 23, 16, (unsigned*)(st + 10));
  scales_kernel<<<1, 1, 0, stream>>>(st, 4);
  final_quant_kernel<<<1024, 256, 0, stream>>>(out, st, n4);
}

// Round 2
// 810.278 us; speedup vs baseline: 1.0353x; 1.0353x over previous
//
#include <hip/hip_runtime.h>

// QuantMHSANet: Brevitas-style per-tensor fake-quant MHSA.
// S=2048 B=4 E=512 H=8 D=64. All GEMMs run as integer-exact bf16 MFMA.
constexpr int cS = 2048, cB = 4, cE = 512, cH = 8, cD = 64;
constexpr int cSB = cS * cB;   // 8192 rows
constexpr int cBH = cB * cH;   // 32 (b,h) pairs
constexpr int cN  = cSB * cE;  // 4194304 elements

typedef __bf16 v8bf  __attribute__((ext_vector_type(8)));
typedef float  f32x4 __attribute__((ext_vector_type(4)));

constexpr float cLOG2E = 1.4426950408889634f;

// ---- stat slots (float) ----
// 0 amax_x | 1..4 amax_w(q,k,v,o) | 5 amax_q 6 amax_k 7 amax_v | 8 max_invz
// 9 amax_ctx | 10 amax_y | 11 s0 | 12 s_in | 13..16 s_w(q,k,v,o) |
// 17 s_q 18 s_k 19 s_v | 20 scale_a 21 inv_scale_a 22 ctx_scale | 23 s_c | 24 s_y |
// 25 s_q*s_k | 26 s_q*s_k*log2e

// Quantized ints |v|<=255 have <=8 significand bits -> bf16 truncation is exact.
__device__ __forceinline__ unsigned short q2bf(float f) {
  return (unsigned short)(__float_as_uint(f) >> 16);
}
__device__ __forceinline__ float clip8(float t) { return fminf(fmaxf(t, -128.f), 127.f); }
__device__ __forceinline__ float wave_max(float v) {
#pragma unroll
  for (int o = 32; o > 0; o >>= 1) v = fmaxf(v, __shfl_down(v, o));
  return v;
}

// ---------------- reductions & scales ----------------
__global__ void absmax_kernel(const float* __restrict__ p, int n4, unsigned* slot) {
  int tid = blockIdx.x * blockDim.x + threadIdx.x, stride = gridDim.x * blockDim.x;
  float m = 0.f;
  for (int i = tid; i < n4; i += stride) {
    float4 v = ((const float4*)p)[i];
    m = fmaxf(m, fmaxf(fmaxf(fabsf(v.x), fabsf(v.y)), fmaxf(fabsf(v.z), fabsf(v.w))));
  }
  m = wave_max(m);
  __shared__ float sm[4];
  int lane = threadIdx.x & 63, wid = threadIdx.x >> 6;
  if (lane == 0) sm[wid] = m;
  __syncthreads();
  if (threadIdx.x == 0) {
    float mm = sm[0];
    for (int w = 1; w < (int)blockDim.x / 64; ++w) mm = fmaxf(mm, sm[w]);
    atomicMax(slot, __float_as_uint(mm));
  }
}

__global__ void scales_kernel(float* st, int stage) {
  if (stage == 0) {
    float s0 = fmaxf(st[0], 1e-8f) / 127.f;
    st[11] = s0;
    float mxq = s0 * 127.f;                 // max|xq| (max int is always 127)
    st[12] = fmaxf(mxq, 1e-8f) / 127.f;     // s_in
    for (int i = 0; i < 4; ++i) st[13 + i] = fmaxf(st[1 + i], 1e-8f) / 127.f;
  } else if (stage == 1) {
    st[17] = fmaxf(st[5] * 0.125f, 1e-8f) / 127.f;  // s_q (q/sqrt(64))
    st[18] = fmaxf(st[6], 1e-8f) / 127.f;           // s_k
    st[19] = fmaxf(st[7], 1e-8f) / 127.f;           // s_v
    st[25] = st[17] * st[18];
    st[26] = st[25] * cLOG2E;
  } else if (stage == 2) {
    float sa = fmaxf(st[8], 1e-8f) / 255.f;         // max(attn)=1/minZ
    st[20] = sa; st[21] = 1.f / sa; st[22] = sa * st[19];
  } else if (stage == 3) {
    st[23] = fmaxf(st[9], 1e-8f) / 127.f;           // s_c
  } else {
    st[24] = fmaxf(st[10], 1e-8f) / 127.f;          // s_y
  }
}

// ---------------- elementwise quantizers ----------------
__global__ void quant_x_kernel(const float* __restrict__ x, unsigned short* __restrict__ xq,
                               const float* st, int n4) {
  float s0 = st[11], si = st[12];
  int tid = blockIdx.x * blockDim.x + threadIdx.x, stride = gridDim.x * blockDim.x;
  for (int i = tid; i < n4; i += stride) {
    float4 v = ((const float4*)x)[i];
    ushort4 o; float t;
    t = s0 * clip8(rintf(v.x / s0)); o.x = q2bf(clip8(rintf(t / si)));
    t = s0 * clip8(rintf(v.y / s0)); o.y = q2bf(clip8(rintf(t / si)));
    t = s0 * clip8(rintf(v.z / s0)); o.z = q2bf(clip8(rintf(t / si)));
    t = s0 * clip8(rintf(v.w / s0)); o.w = q2bf(clip8(rintf(t / si)));
    ((ushort4*)xq)[i] = o;
  }
}

__global__ void quant_s8_kernel(const float* __restrict__ in, unsigned short* __restrict__ outp,
                                int n4, const float* st, int slot, float premul) {
  float s = st[slot];
  int tid = blockIdx.x * blockDim.x + threadIdx.x, stride = gridDim.x * blockDim.x;
  for (int i = tid; i < n4; i += stride) {
    float4 v = ((const float4*)in)[i];
    ushort4 o;
    o.x = q2bf(clip8(rintf(v.x * premul / s)));
    o.y = q2bf(clip8(rintf(v.y * premul / s)));
    o.z = q2bf(clip8(rintf(v.z * premul / s)));
    o.w = q2bf(clip8(rintf(v.w * premul / s)));
    ((ushort4*)outp)[i] = o;
  }
}

__global__ void bias_kernel(const float* __restrict__ bsrc, float* __restrict__ bdst,
                            const float* st, int slot_in, int slot_w) {
  int f = blockIdx.x * blockDim.x + threadIdx.x;
  if (f < cE) {
    float s = st[slot_in] * st[slot_w];
    bdst[f] = s * rintf(bsrc[f] / s);   // int32 clip is a no-op at these magnitudes
  }
}

// V: [BH][S][D] f32 -> quantized, transposed [BH][D][S] bf16 (K-major for PV B-frags)
__global__ __launch_bounds__(256) void quant_vT_kernel(const float* __restrict__ v,
                                                       unsigned short* __restrict__ vT,
                                                       const float* st) {
  __shared__ unsigned short tile[64][65];
  int bh = blockIdx.y, s0 = blockIdx.x * 64;
  float sv = st[19];
  int td = threadIdx.x & 63, tr = threadIdx.x >> 6;
  for (int r = tr; r < 64; r += 4)
    tile[r][td] = q2bf(clip8(rintf(v[((size_t)bh * cS + s0 + r) * cD + td] / sv)));
  __syncthreads();
  for (int r = tr; r < 64; r += 4)
    vT[((size_t)bh * cD + r) * cS + s0 + td] = tile[td][r];
}

__global__ void final_quant_kernel(float* __restrict__ y, const float* st, int n4) {
  float s = st[24];
  int tid = blockIdx.x * blockDim.x + threadIdx.x, stride = gridDim.x * blockDim.x;
  for (int i = tid; i < n4; i += stride) {
    float4 v = ((float4*)y)[i];
    v.x = s * clip8(rintf(v.x / s)); v.y = s * clip8(rintf(v.y / s));
    v.z = s * clip8(rintf(v.z / s)); v.w = s * clip8(rintf(v.w / s));
    ((float4*)y)[i] = v;
  }
}

// ---------------- integer-exact bf16 MFMA GEMM ----------------
// C[row,col] = sum_e A[row][e]*W[col][e]; both stored K-major (512 cols bf16-int).
// OUTMODE 0: write [B][H][S][D] (heads split) ; OUTMODE 1: write row-major [SB][E].
template <int OUTMODE>
__global__ __launch_bounds__(256) void gemm_kernel(const unsigned short* __restrict__ A,
                                                   const unsigned short* __restrict__ Wb,
                                                   const float* __restrict__ bias,
                                                   float* __restrict__ out, const float* st,
                                                   int slot_in, int slot_w, unsigned* amax_slot) {
  int wid = threadIdx.x >> 6, lane = threadIdx.x & 63;
  int wm = wid >> 1, wn = wid & 1;
  int row0 = blockIdx.x * 64 + wm * 32;
  int col0 = blockIdx.y * 64 + wn * 32;
  int lr = lane & 15, lk = (lane >> 4) * 8;
  f32x4 acc[2][2] = {};
  const unsigned short* a0p = A + (size_t)(row0 + lr) * cE + lk;
  const unsigned short* a1p = A + (size_t)(row0 + 16 + lr) * cE + lk;
  const unsigned short* b0p = Wb + (size_t)(col0 + lr) * cE + lk;
  const unsigned short* b1p = Wb + (size_t)(col0 + 16 + lr) * cE + lk;
  for (int e0 = 0; e0 < cE; e0 += 32) {
    v8bf a0 = *(const v8bf*)(a0p + e0), a1 = *(const v8bf*)(a1p + e0);
    v8bf b0 = *(const v8bf*)(b0p + e0), b1 = *(const v8bf*)(b1p + e0);
    acc[0][0] = __builtin_amdgcn_mfma_f32_16x16x32_bf16(a0, b0, acc[0][0], 0, 0, 0);
    acc[0][1] = __builtin_amdgcn_mfma_f32_16x16x32_bf16(a0, b1, acc[0][1], 0, 0, 0);
    acc[1][0] = __builtin_amdgcn_mfma_f32_16x16x32_bf16(a1, b0, acc[1][0], 0, 0, 0);
    acc[1][1] = __builtin_amdgcn_mfma_f32_16x16x32_bf16(a1, b1, acc[1][1], 0, 0, 0);
  }
  float scale = st[slot_in] * st[slot_w];
  float lmax = 0.f;
#pragma unroll
  for (int mi = 0; mi < 2; ++mi)
#pragma unroll
    for (int ni = 0; ni < 2; ++ni)
#pragma unroll
      for (int r = 0; r < 4; ++r) {
        int row = row0 + mi * 16 + (lane >> 4) * 4 + r;   // C/D: row=(l>>4)*4+reg
        int col = col0 + ni * 16 + lr;                    //      col=l&15
        float val = scale * acc[mi][ni][r] + bias[col];
        lmax = fmaxf(lmax, fabsf(val));
        if (OUTMODE == 0) {
          int s = row >> 2, bb = row & 3, h = col >> 6, d = col & 63;
          out[(((size_t)(bb * cH + h)) * cS + s) * cD + d] = val;
        } else {
          out[(size_t)row * cE + col] = val;
        }
      }
  lmax = wave_max(lmax);
  if (lane == 0) atomicMax(amax_slot, __float_as_uint(lmax));
}

// ---------------- attention pass 1: per-row (m2, 1/Z) in log2 domain ----------------
// Per-lane online softmax over this lane's 4 columns/tile; one 16-lane merge at end.
__global__ __launch_bounds__(256) void attn_pass1_kernel(const unsigned short* __restrict__ qs,
                                                         const unsigned short* __restrict__ ks,
                                                         float* __restrict__ marr,
                                                         float* __restrict__ izarr,
                                                         const float* st, unsigned* maxiz_slot) {
  int bh = blockIdx.y;
  int wid = threadIdx.x >> 6, lane = threadIdx.x & 63;
  int lr = lane & 15, lk = (lane >> 4) * 8;
  int r0 = blockIdx.x * 64 + wid * 16;
  float sscale2 = st[26];   // s_q*s_k*log2e  (log2-domain scores)
  v8bf aq0 = *(const v8bf*)(qs + ((size_t)bh * cS + r0 + lr) * cD + lk);
  v8bf aq1 = *(const v8bf*)(qs + ((size_t)bh * cS + r0 + lr) * cD + 32 + lk);
  float pm[4] = {-1e30f, -1e30f, -1e30f, -1e30f};
  float zs[4] = {0.f, 0.f, 0.f, 0.f};
  for (int kt = 0; kt < cS; kt += 64) {
    f32x4 sc[4];
#pragma unroll
    for (int jc = 0; jc < 4; ++jc) {
      const unsigned short* kb = ks + ((size_t)bh * cS + kt + jc * 16 + lr) * cD + lk;
      v8bf b0 = *(const v8bf*)kb, b1 = *(const v8bf*)(kb + 32);
      f32x4 z = {0.f, 0.f, 0.f, 0.f};
      z = __builtin_amdgcn_mfma_f32_16x16x32_bf16(aq0, b0, z, 0, 0, 0);
      z = __builtin_amdgcn_mfma_f32_16x16x32_bf16(aq1, b1, z, 0, 0, 0);
      sc[jc] = z;
    }
#pragma unroll
    for (int r = 0; r < 4; ++r) {
      float v0 = sc[0][r] * sscale2, v1 = sc[1][r] * sscale2;
      float v2 = sc[2][r] * sscale2, v3 = sc[3][r] * sscale2;
      float tm = fmaxf(fmaxf(v0, v1), fmaxf(v2, v3));
      float nm = fmaxf(pm[r], tm);
      zs[r] = zs[r] * __builtin_amdgcn_exp2f(pm[r] - nm) +
              __builtin_amdgcn_exp2f(v0 - nm) + __builtin_amdgcn_exp2f(v1 - nm) +
              __builtin_amdgcn_exp2f(v2 - nm) + __builtin_amdgcn_exp2f(v3 - nm);
      pm[r] = nm;
    }
  }
  float wmax = 0.f;
#pragma unroll
  for (int r = 0; r < 4; ++r) {
    float m = pm[r], z = zs[r];
#pragma unroll
    for (int o = 1; o < 16; o <<= 1) {
      float mo = __shfl_xor(m, o);
      float zo = __shfl_xor(z, o);
      float nm = fmaxf(m, mo);
      z = z * __builtin_amdgcn_exp2f(m - nm) + zo * __builtin_amdgcn_exp2f(mo - nm);
      m = nm;
    }
    if (lr == 0) {
      int row = r0 + (lane >> 4) * 4 + r;
      float iz = 1.0f / z;
      marr[bh * cS + row] = m;       // log2-domain row max
      izarr[bh * cS + row] = iz;
      wmax = fmaxf(wmax, iz);
    }
  }
  wmax = wave_max(wmax);
  if (lane == 0) atomicMax(maxiz_slot, __float_as_uint(wmax));
}

// ---------------- attention pass 2: P=u8-quant(softmax) ; ctx += P*V ----------------
// plds is wave-private (double-buffered) -> no __syncthreads; per-wave DS ordering +
// lgkmcnt(0) covers the write->read edge (rule #18: sched_barrier after the wait).
__global__ __launch_bounds__(256) void attn_pass2_kernel(
    const unsigned short* __restrict__ qs, const unsigned short* __restrict__ ks,
    const unsigned short* __restrict__ vT, const float* __restrict__ marr,
    const float* __restrict__ izarr, float* __restrict__ ctx, const float* st,
    unsigned* amax_slot) {
  __shared__ __align__(16) unsigned short plds[4][2][16][72];
  int bh = blockIdx.y, b = bh >> 3, h = bh & 7;
  int wid = threadIdx.x >> 6, lane = threadIdx.x & 63;
  int lr = lane & 15, lk = (lane >> 4) * 8;
  int r0 = blockIdx.x * 64 + wid * 16;
  float sscale2 = st[26], isa = st[21], cscale = st[22];
  v8bf aq0 = *(const v8bf*)(qs + ((size_t)bh * cS + r0 + lr) * cD + lk);
  v8bf aq1 = *(const v8bf*)(qs + ((size_t)bh * cS + r0 + lr) * cD + 32 + lk);
  float m2[4], fac[4];
  int rowbase = bh * cS + r0 + (lane >> 4) * 4;
#pragma unroll
  for (int r = 0; r < 4; ++r) {
    m2[r] = marr[rowbase + r];
    fac[r] = izarr[rowbase + r] * isa;
  }
  f32x4 cacc[4] = {};
  int buf = 0;
  for (int kt = 0; kt < cS; kt += 64, buf ^= 1) {
    f32x4 sc[4];
#pragma unroll
    for (int jc = 0; jc < 4; ++jc) {
      const unsigned short* kb = ks + ((size_t)bh * cS + kt + jc * 16 + lr) * cD + lk;
      v8bf b0 = *(const v8bf*)kb, b1 = *(const v8bf*)(kb + 32);
      f32x4 z = {0.f, 0.f, 0.f, 0.f};
      z = __builtin_amdgcn_mfma_f32_16x16x32_bf16(aq0, b0, z, 0, 0, 0);
      z = __builtin_amdgcn_mfma_f32_16x16x32_bf16(aq1, b1, z, 0, 0, 0);
      sc[jc] = z;
    }
    unsigned short (*pl)[72] = plds[wid][buf];
#pragma unroll
    for (int jc = 0; jc < 4; ++jc)
#pragma unroll
      for (int r = 0; r < 4; ++r) {
        float t = __builtin_fmaf(sc[jc][r], sscale2, -m2[r]);
        float e = __builtin_amdgcn_exp2f(t);
        float a = fminf(rintf(e * fac[r]), 255.f);   // e*fac >= 0
        pl[(lane >> 4) * 4 + r][jc * 16 + lr] = q2bf(a);
      }
    asm volatile("s_waitcnt lgkmcnt(0)" ::: "memory");
    __builtin_amdgcn_sched_barrier(0);
    v8bf ap0 = *(const v8bf*)&pl[lr][lk];
    v8bf ap1 = *(const v8bf*)&pl[lr][32 + lk];
#pragma unroll
    for (int dt = 0; dt < 4; ++dt) {
      const unsigned short* vb = vT + ((size_t)bh * cD + dt * 16 + lr) * cS + kt + lk;
      v8bf bv0 = *(const v8bf*)vb, bv1 = *(const v8bf*)(vb + 32);
      cacc[dt] = __builtin_amdgcn_mfma_f32_16x16x32_bf16(ap0, bv0, cacc[dt], 0, 0, 0);
      cacc[dt] = __builtin_amdgcn_mfma_f32_16x16x32_bf16(ap1, bv1, cacc[dt], 0, 0, 0);
    }
  }
  float lmax = 0.f;
#pragma unroll
  for (int dt = 0; dt < 4; ++dt)
#pragma unroll
    for (int r = 0; r < 4; ++r) {
      int qrow = r0 + (lane >> 4) * 4 + r;
      int d = dt * 16 + lr;
      float val = cscale * cacc[dt][r];
      lmax = fmaxf(lmax, fabsf(val));
      ctx[((size_t)qrow * cB + b) * cE + h * cD + d] = val;  // [S][B][E]
    }
  lmax = wave_max(lmax);
  if (lane == 0) atomicMax(amax_slot, __float_as_uint(lmax));
}

// ---------------- launcher ----------------
extern "C" void kernel_launch(void* const* d_in, const int* in_sizes, int n_in, void* d_out,
                              int out_size, void* d_ws, size_t ws_size, hipStream_t stream) {
  (void)in_sizes; (void)n_in; (void)out_size; (void)ws_size;
  const float* x  = (const float*)d_in[0];
  const float* Wq = (const float*)d_in[1];
  const float* Wk = (const float*)d_in[2];
  const float* Wv = (const float*)d_in[3];
  const float* bq = (const float*)d_in[4];
  const float* bk = (const float*)d_in[5];
  const float* bv = (const float*)d_in[6];
  const float* Wo = (const float*)d_in[7];
  const float* bo = (const float*)d_in[8];
  float* out = (float*)d_out;

  char* ws = (char*)d_ws;
  size_t off = 0;
  auto alloc = [&](size_t bytes) { size_t o = off; off += (bytes + 255) & ~(size_t)255; return o; };
  float* st = (float*)(ws + alloc(64 * 4));
  unsigned short* xq  = (unsigned short*)(ws + alloc((size_t)cN * 2));
  unsigned short* wbq = (unsigned short*)(ws + alloc((size_t)cE * cE * 2));
  unsigned short* wbk = (unsigned short*)(ws + alloc((size_t)cE * cE * 2));
  unsigned short* wbv = (unsigned short*)(ws + alloc((size_t)cE * cE * 2));
  unsigned short* wbo = (unsigned short*)(ws + alloc((size_t)cE * cE * 2));
  float* bfq = (float*)(ws + alloc(cE * 4));
  float* bfk = (float*)(ws + alloc(cE * 4));
  float* bfv = (float*)(ws + alloc(cE * 4));
  float* bfo = (float*)(ws + alloc(cE * 4));
  float* qf = (float*)(ws + alloc((size_t)cN * 4));   // [BH][S][D]
  float* kf = (float*)(ws + alloc((size_t)cN * 4));
  float* vf = (float*)(ws + alloc((size_t)cN * 4));
  unsigned short* qsb = (unsigned short*)(ws + alloc((size_t)cN * 2));
  unsigned short* ksb = (unsigned short*)(ws + alloc((size_t)cN * 2));
  unsigned short* vTb = (unsigned short*)(ws + alloc((size_t)cN * 2));
  float* marr  = (float*)(ws + alloc((size_t)cBH * cS * 4));
  float* izarr = (float*)(ws + alloc((size_t)cBH * cS * 4));
  float* ctxf = qf;                      // alias: qf dead after quant(q)
  unsigned short* cib = (unsigned short*)kf;  // alias: kf dead after quant(k)
  // total ws ~ 87 MB

  int n4 = cN / 4;
  hipMemsetAsync(st, 0, 256, stream);
  absmax_kernel<<<1024, 256, 0, stream>>>(x, n4, (unsigned*)(st + 0));
  absmax_kernel<<<256, 256, 0, stream>>>(Wq, cE * cE / 4, (unsigned*)(st + 1));
  absmax_kernel<<<256, 256, 0, stream>>>(Wk, cE * cE / 4, (unsigned*)(st + 2));
  absmax_kernel<<<256, 256, 0, stream>>>(Wv, cE * cE / 4, (unsigned*)(st + 3));
  absmax_kernel<<<256, 256, 0, stream>>>(Wo, cE * cE / 4, (unsigned*)(st + 4));
  scales_kernel<<<1, 1, 0, stream>>>(st, 0);
  quant_x_kernel<<<1024, 256, 0, stream>>>(x, xq, st, n4);
  quant_s8_kernel<<<256, 256, 0, stream>>>(Wq, wbq, cE * cE / 4, st, 13, 1.0f);
  quant_s8_kernel<<<256, 256, 0, stream>>>(Wk, wbk, cE * cE / 4, st, 14, 1.0f);
  quant_s8_kernel<<<256, 256, 0, stream>>>(Wv, wbv, cE * cE / 4, st, 15, 1.0f);
  quant_s8_kernel<<<256, 256, 0, stream>>>(Wo, wbo, cE * cE / 4, st, 16, 1.0f);
  bias_kernel<<<2, 256, 0, stream>>>(bq, bfq, st, 12, 13);
  bias_kernel<<<2, 256, 0, stream>>>(bk, bfk, st, 12, 14);
  bias_kernel<<<2, 256, 0, stream>>>(bv, bfv, st, 12, 15);
  gemm_kernel<0><<<dim3(cSB / 64, cE / 64), 256, 0, stream>>>(xq, wbq, bfq, qf, st, 12, 13, (unsigned*)(st + 5));
  gemm_kernel<0><<<dim3(cSB / 64, cE / 64), 256, 0, stream>>>(xq, wbk, bfk, kf, st, 12, 14, (unsigned*)(st + 6));
  gemm_kernel<0><<<dim3(cSB / 64, cE / 64), 256, 0, stream>>>(xq, wbv, bfv, vf, st, 12, 15, (unsigned*)(st + 7));
  scales_kernel<<<1, 1, 0, stream>>>(st, 1);
  quant_s8_kernel<<<1024, 256, 0, stream>>>(qf, qsb, n4, st, 17, 0.125f);
  quant_s8_kernel<<<1024, 256, 0, stream>>>(kf, ksb, n4, st, 18, 1.0f);
  quant_vT_kernel<<<dim3(cS / 64, cBH), 256, 0, stream>>>(vf, vTb, st);
  attn_pass1_kernel<<<dim3(cS / 64, cBH), 256, 0, stream>>>(qsb, ksb, marr, izarr, st, (unsigned*)(st + 8));
  scales_kernel<<<1, 1, 0, stream>>>(st, 2);
  attn_pass2_kernel<<<dim3(cS / 64, cBH), 256, 0, stream>>>(qsb, ksb, vTb, marr, izarr, ctxf, st, (unsigned*)(st + 9));
  scales_kernel<<<1, 1, 0, stream>>>(st, 3);
  quant_s8_kernel<<<1024, 256, 0, stream>>>(ctxf, cib, n4, st, 23, 1.0f);
  bias_kernel<<<2, 256, 0, stream>>>(bo, bfo, st, 23, 16);
  gemm_kernel<1><<<dim3(cSB / 64, cE / 64), 256, 0, stream>>>(cib, wbo, bfo, out, st, 23, 16, (unsigned*)(st + 10));
  scales_kernel<<<1, 1, 0, stream>>>(st, 4);
  final_quant_kernel<<<1024, 256, 0, stream>>>(out, st, n4);
}

// Round 4
// 763.681 us; speedup vs baseline: 1.0985x; 1.0610x over previous
//
#include <hip/hip_runtime.h>

// QuantMHSANet: Brevitas-style per-tensor fake-quant MHSA.
// S=2048 B=4 E=512 H=8 D=64. All GEMMs run as integer-exact bf16 MFMA.
constexpr int cS = 2048, cB = 4, cE = 512, cH = 8, cD = 64;
constexpr int cSB = cS * cB;   // 8192 rows
constexpr int cBH = cB * cH;   // 32 (b,h) pairs
constexpr int cN  = cSB * cE;  // 4194304 elements

typedef __bf16 v8bf  __attribute__((ext_vector_type(8)));
typedef float  f32x4 __attribute__((ext_vector_type(4)));

constexpr float cLOG2E = 1.4426950408889634f;

// ---- stat slots (float) ----
// 0 amax_x | 1..4 amax_w(q,k,v,o) | 5 amax_q 6 amax_k 7 amax_v | 8 max_invz
// 9 amax_ctx | 10 amax_y | 11 s0 | 12 s_in | 13..16 s_w(q,k,v,o) |
// 17 s_q 18 s_k 19 s_v | 20 scale_a 21 inv_scale_a 22 ctx_scale | 23 s_c | 24 s_y |
// 25 s_q*s_k | 26 s_q*s_k*log2e

// Quantized ints |v|<=255 have <=8 significand bits -> bf16 truncation is exact.
__device__ __forceinline__ unsigned short q2bf(float f) {
  return (unsigned short)(__float_as_uint(f) >> 16);
}
__device__ __forceinline__ float clip8(float t) { return fminf(fmaxf(t, -128.f), 127.f); }
__device__ __forceinline__ float wave_max(float v) {
#pragma unroll
  for (int o = 32; o > 0; o >>= 1) v = fmaxf(v, __shfl_down(v, o));
  return v;
}

// ---------------- reductions & scales ----------------
__global__ void absmax_kernel(const float* __restrict__ p, int n4, unsigned* slot) {
  int tid = blockIdx.x * blockDim.x + threadIdx.x, stride = gridDim.x * blockDim.x;
  float m = 0.f;
  for (int i = tid; i < n4; i += stride) {
    float4 v = ((const float4*)p)[i];
    m = fmaxf(m, fmaxf(fmaxf(fabsf(v.x), fabsf(v.y)), fmaxf(fabsf(v.z), fabsf(v.w))));
  }
  m = wave_max(m);
  __shared__ float sm[4];
  int lane = threadIdx.x & 63, wid = threadIdx.x >> 6;
  if (lane == 0) sm[wid] = m;
  __syncthreads();
  if (threadIdx.x == 0) {
    float mm = sm[0];
    for (int w = 1; w < (int)blockDim.x / 64; ++w) mm = fmaxf(mm, sm[w]);
    atomicMax(slot, __float_as_uint(mm));
  }
}

// 4 weight matrices in one launch (blockIdx.y selects)
__global__ void absmax4_kernel(const float* __restrict__ w0, const float* __restrict__ w1,
                               const float* __restrict__ w2, const float* __restrict__ w3,
                               int n4, unsigned* slots) {
  int y = blockIdx.y;
  const float* p = (y == 0) ? w0 : (y == 1) ? w1 : (y == 2) ? w2 : w3;
  int tid = blockIdx.x * blockDim.x + threadIdx.x, stride = gridDim.x * blockDim.x;
  float m = 0.f;
  for (int i = tid; i < n4; i += stride) {
    float4 v = ((const float4*)p)[i];
    m = fmaxf(m, fmaxf(fmaxf(fabsf(v.x), fabsf(v.y)), fmaxf(fabsf(v.z), fabsf(v.w))));
  }
  m = wave_max(m);
  __shared__ float sm[4];
  int lane = threadIdx.x & 63, wid = threadIdx.x >> 6;
  if (lane == 0) sm[wid] = m;
  __syncthreads();
  if (threadIdx.x == 0) {
    float mm = fmaxf(fmaxf(sm[0], sm[1]), fmaxf(sm[2], sm[3]));
    atomicMax(slots + y, __float_as_uint(mm));
  }
}

__global__ void scales_kernel(float* st, int stage) {
  if (stage == 0) {
    float s0 = fmaxf(st[0], 1e-8f) / 127.f;
    st[11] = s0;
    float mxq = s0 * 127.f;                 // max|xq| (max int is always 127)
    st[12] = fmaxf(mxq, 1e-8f) / 127.f;     // s_in
    for (int i = 0; i < 4; ++i) st[13 + i] = fmaxf(st[1 + i], 1e-8f) / 127.f;
  } else if (stage == 1) {
    st[17] = fmaxf(st[5] * 0.125f, 1e-8f) / 127.f;  // s_q (q/sqrt(64))
    st[18] = fmaxf(st[6], 1e-8f) / 127.f;           // s_k
    st[19] = fmaxf(st[7], 1e-8f) / 127.f;           // s_v
    st[25] = st[17] * st[18];
    st[26] = st[25] * cLOG2E;
  } else if (stage == 2) {
    float sa = fmaxf(st[8], 1e-8f) / 255.f;         // max(attn)=1/minZ
    st[20] = sa; st[21] = 1.f / sa; st[22] = sa * st[19];
  } else if (stage == 3) {
    st[23] = fmaxf(st[9], 1e-8f) / 127.f;           // s_c
  } else {
    st[24] = fmaxf(st[10], 1e-8f) / 127.f;          // s_y
  }
}

// ---------------- elementwise quantizers ----------------
__global__ void quant_x_kernel(const float* __restrict__ x, unsigned short* __restrict__ xq,
                               const float* st, int n4) {
  float s0 = st[11], si = st[12];
  int tid = blockIdx.x * blockDim.x + threadIdx.x, stride = gridDim.x * blockDim.x;
  for (int i = tid; i < n4; i += stride) {
    float4 v = ((const float4*)x)[i];
    ushort4 o; float t;
    t = s0 * clip8(rintf(v.x / s0)); o.x = q2bf(clip8(rintf(t / si)));
    t = s0 * clip8(rintf(v.y / s0)); o.y = q2bf(clip8(rintf(t / si)));
    t = s0 * clip8(rintf(v.z / s0)); o.z = q2bf(clip8(rintf(t / si)));
    t = s0 * clip8(rintf(v.w / s0)); o.w = q2bf(clip8(rintf(t / si)));
    ((ushort4*)xq)[i] = o;
  }
}

// 4 weight matrices quantized in one launch; outputs contiguous at outbase + y*cE*cE
__global__ void quant_w4_kernel(const float* __restrict__ w0, const float* __restrict__ w1,
                                const float* __restrict__ w2, const float* __restrict__ w3,
                                unsigned short* __restrict__ outbase, int n4, const float* st) {
  int y = blockIdx.y;
  const float* in = (y == 0) ? w0 : (y == 1) ? w1 : (y == 2) ? w2 : w3;
  unsigned short* outp = outbase + (size_t)y * cE * cE;
  float s = st[13 + y];
  int tid = blockIdx.x * blockDim.x + threadIdx.x, stride = gridDim.x * blockDim.x;
  for (int i = tid; i < n4; i += stride) {
    float4 v = ((const float4*)in)[i];
    ushort4 o;
    o.x = q2bf(clip8(rintf(v.x / s)));
    o.y = q2bf(clip8(rintf(v.y / s)));
    o.z = q2bf(clip8(rintf(v.z / s)));
    o.w = q2bf(clip8(rintf(v.w / s)));
    ((ushort4*)outp)[i] = o;
  }
}

__global__ void quant_s8_kernel(const float* __restrict__ in, unsigned short* __restrict__ outp,
                                int n4, const float* st, int slot, float premul) {
  float s = st[slot];
  int tid = blockIdx.x * blockDim.x + threadIdx.x, stride = gridDim.x * blockDim.x;
  for (int i = tid; i < n4; i += stride) {
    float4 v = ((const float4*)in)[i];
    ushort4 o;
    o.x = q2bf(clip8(rintf(v.x * premul / s)));
    o.y = q2bf(clip8(rintf(v.y * premul / s)));
    o.z = q2bf(clip8(rintf(v.z * premul / s)));
    o.w = q2bf(clip8(rintf(v.w * premul / s)));
    ((ushort4*)outp)[i] = o;
  }
}

// q and k quantized in one launch (blockIdx.y: 0=q premul 1/8 slot17, 1=k slot18)
__global__ void quant_qk_kernel(const float* __restrict__ qf, unsigned short* __restrict__ qsb,
                                int n4, const float* st) {
  int y = blockIdx.y;
  const float* in = qf + (size_t)y * cN;
  unsigned short* outp = qsb + (size_t)y * cN;
  float s = st[17 + y];
  float premul = y ? 1.0f : 0.125f;
  int tid = blockIdx.x * blockDim.x + threadIdx.x, stride = gridDim.x * blockDim.x;
  for (int i = tid; i < n4; i += stride) {
    float4 v = ((const float4*)in)[i];
    ushort4 o;
    o.x = q2bf(clip8(rintf(v.x * premul / s)));
    o.y = q2bf(clip8(rintf(v.y * premul / s)));
    o.z = q2bf(clip8(rintf(v.z * premul / s)));
    o.w = q2bf(clip8(rintf(v.w * premul / s)));
    ((ushort4*)outp)[i] = o;
  }
}

// q/k/v biases in one launch; outputs contiguous at bdst + y*512
__global__ void bias3_kernel(const float* __restrict__ b0, const float* __restrict__ b1,
                             const float* __restrict__ b2, float* __restrict__ bdst,
                             const float* st) {
  int y = blockIdx.y;
  const float* bsrc = (y == 0) ? b0 : (y == 1) ? b1 : b2;
  int f = blockIdx.x * blockDim.x + threadIdx.x;
  if (f < cE) {
    float s = st[12] * st[13 + y];
    bdst[y * cE + f] = s * rintf(bsrc[f] / s);
  }
}

__global__ void bias_kernel(const float* __restrict__ bsrc, float* __restrict__ bdst,
                            const float* st, int slot_in, int slot_w) {
  int f = blockIdx.x * blockDim.x + threadIdx.x;
  if (f < cE) {
    float s = st[slot_in] * st[slot_w];
    bdst[f] = s * rintf(bsrc[f] / s);   // int32 clip is a no-op at these magnitudes
  }
}

// V: [BH][S][D] f32 -> quantized, transposed [BH][D][S] bf16 (K-major for PV B-frags)
__global__ __launch_bounds__(256) void quant_vT_kernel(const float* __restrict__ v,
                                                       unsigned short* __restrict__ vT,
                                                       const float* st) {
  __shared__ unsigned short tile[64][65];
  int bh = blockIdx.y, s0 = blockIdx.x * 64;
  float sv = st[19];
  int td = threadIdx.x & 63, tr = threadIdx.x >> 6;
  for (int r = tr; r < 64; r += 4)
    tile[r][td] = q2bf(clip8(rintf(v[((size_t)bh * cS + s0 + r) * cD + td] / sv)));
  __syncthreads();
  for (int r = tr; r < 64; r += 4)
    vT[((size_t)bh * cD + r) * cS + s0 + td] = tile[td][r];
}

__global__ void final_quant_kernel(float* __restrict__ y, const float* st, int n4) {
  float s = st[24];
  int tid = blockIdx.x * blockDim.x + threadIdx.x, stride = gridDim.x * blockDim.x;
  for (int i = tid; i < n4; i += stride) {
    float4 v = ((float4*)y)[i];
    v.x = s * clip8(rintf(v.x / s)); v.y = s * clip8(rintf(v.y / s));
    v.z = s * clip8(rintf(v.z / s)); v.w = s * clip8(rintf(v.w / s));
    ((float4*)y)[i] = v;
  }
}

// ---------------- integer-exact bf16 MFMA GEMM ----------------
// C[row,col] = sum_e A[row][e]*W[col][e]; both stored K-major (512 cols bf16-int).
// OUTMODE 0: write [B][H][S][D] (heads split) ; OUTMODE 1: write row-major [SB][E].
template <int OUTMODE>
__global__ __launch_bounds__(256) void gemm_kernel(const unsigned short* __restrict__ A,
                                                   const unsigned short* __restrict__ Wb,
                                                   const float* __restrict__ bias,
                                                   float* __restrict__ out, const float* st,
                                                   int slot_in, int slot_w, unsigned* amax_slot) {
  int wid = threadIdx.x >> 6, lane = threadIdx.x & 63;
  int wm = wid >> 1, wn = wid & 1;
  int row0 = blockIdx.x * 64 + wm * 32;
  int col0 = blockIdx.y * 64 + wn * 32;
  int lr = lane & 15, lk = (lane >> 4) * 8;
  f32x4 acc[2][2] = {};
  const unsigned short* a0p = A + (size_t)(row0 + lr) * cE + lk;
  const unsigned short* a1p = A + (size_t)(row0 + 16 + lr) * cE + lk;
  const unsigned short* b0p = Wb + (size_t)(col0 + lr) * cE + lk;
  const unsigned short* b1p = Wb + (size_t)(col0 + 16 + lr) * cE + lk;
  for (int e0 = 0; e0 < cE; e0 += 32) {
    v8bf a0 = *(const v8bf*)(a0p + e0), a1 = *(const v8bf*)(a1p + e0);
    v8bf b0 = *(const v8bf*)(b0p + e0), b1 = *(const v8bf*)(b1p + e0);
    acc[0][0] = __builtin_amdgcn_mfma_f32_16x16x32_bf16(a0, b0, acc[0][0], 0, 0, 0);
    acc[0][1] = __builtin_amdgcn_mfma_f32_16x16x32_bf16(a0, b1, acc[0][1], 0, 0, 0);
    acc[1][0] = __builtin_amdgcn_mfma_f32_16x16x32_bf16(a1, b0, acc[1][0], 0, 0, 0);
    acc[1][1] = __builtin_amdgcn_mfma_f32_16x16x32_bf16(a1, b1, acc[1][1], 0, 0, 0);
  }
  float scale = st[slot_in] * st[slot_w];
  float lmax = 0.f;
#pragma unroll
  for (int mi = 0; mi < 2; ++mi)
#pragma unroll
    for (int ni = 0; ni < 2; ++ni)
#pragma unroll
      for (int r = 0; r < 4; ++r) {
        int row = row0 + mi * 16 + (lane >> 4) * 4 + r;   // C/D: row=(l>>4)*4+reg
        int col = col0 + ni * 16 + lr;                    //      col=l&15
        float val = scale * acc[mi][ni][r] + bias[col];
        lmax = fmaxf(lmax, fabsf(val));
        if (OUTMODE == 0) {
          int s = row >> 2, bb = row & 3, h = col >> 6, d = col & 63;
          out[(((size_t)(bb * cH + h)) * cS + s) * cD + d] = val;
        } else {
          out[(size_t)row * cE + col] = val;
        }
      }
  lmax = wave_max(lmax);
  if (lane == 0) atomicMax(amax_slot, __float_as_uint(lmax));
}

// ---------------- attention pass 1: per-row (m2, 1/Z) in log2 domain ----------------
// Swapped QK (A=K frag, B=Q frag): each lane owns q-row = lane&15, k = (lane>>4)*4+r
// per 16-block. Fully per-lane online softmax; 2-step cross-group merge at the end.
// K tiles register-prefetched one iteration ahead.
__global__ __launch_bounds__(256) void attn_pass1_kernel(const unsigned short* __restrict__ qs,
                                                         const unsigned short* __restrict__ ks,
                                                         float* __restrict__ marr,
                                                         float* __restrict__ izarr,
                                                         const float* st, unsigned* maxiz_slot) {
  int bh = blockIdx.y;
  int wid = threadIdx.x >> 6, lane = threadIdx.x & 63;
  int lr = lane & 15, g = lane >> 4, lk = g * 8;
  int r0 = blockIdx.x * 64 + wid * 16;
  float sscale2 = st[26];   // s_q*s_k*log2e  (log2-domain scores)
  v8bf aq0 = *(const v8bf*)(qs + ((size_t)bh * cS + r0 + lr) * cD + lk);
  v8bf aq1 = *(const v8bf*)(qs + ((size_t)bh * cS + r0 + lr) * cD + 32 + lk);
  const unsigned short* Kbase = ks + (size_t)bh * cS * cD;

  v8bf K0[4], K1[4];
#pragma unroll
  for (int jc = 0; jc < 4; ++jc) {
    const unsigned short* p = Kbase + (size_t)(jc * 16 + lr) * cD + lk;
    K0[jc] = *(const v8bf*)p; K1[jc] = *(const v8bf*)(p + 32);
  }
  float pm = -1e30f, zs = 0.f;
  for (int kt = 0; kt < cS; kt += 64) {
    f32x4 s4[4];
#pragma unroll
    for (int jc = 0; jc < 4; ++jc) {
      f32x4 z = {0.f, 0.f, 0.f, 0.f};
      z = __builtin_amdgcn_mfma_f32_16x16x32_bf16(K0[jc], aq0, z, 0, 0, 0);
      z = __builtin_amdgcn_mfma_f32_16x16x32_bf16(K1[jc], aq1, z, 0, 0, 0);
      s4[jc] = z;
    }
    // prefetch next K tile (last iter reads past ks into vTb scratch — values unused)
#pragma unroll
    for (int jc = 0; jc < 4; ++jc) {
      const unsigned short* p = Kbase + (size_t)(kt + 64 + jc * 16 + lr) * cD + lk;
      K0[jc] = *(const v8bf*)p; K1[jc] = *(const v8bf*)(p + 32);
    }
    float t[16];
#pragma unroll
    for (int jc = 0; jc < 4; ++jc)
#pragma unroll
      for (int r = 0; r < 4; ++r) t[jc * 4 + r] = s4[jc][r] * sscale2;
    float tm = t[0];
#pragma unroll
    for (int i = 1; i < 16; ++i) tm = fmaxf(tm, t[i]);
    float nm = fmaxf(pm, tm);
    float acc = zs * __builtin_amdgcn_exp2f(pm - nm);
#pragma unroll
    for (int i = 0; i < 16; ++i) acc += __builtin_amdgcn_exp2f(t[i] - nm);
    zs = acc; pm = nm;
  }
  // merge the 4 groups (lanes lr, lr+16, lr+32, lr+48)
#pragma unroll
  for (int o = 16; o < 64; o <<= 1) {
    float mo = __shfl_xor(pm, o);
    float zo = __shfl_xor(zs, o);
    float nm = fmaxf(pm, mo);
    zs = zs * __builtin_amdgcn_exp2f(pm - nm) + zo * __builtin_amdgcn_exp2f(mo - nm);
    pm = nm;
  }
  float iz = 1.0f / zs;
  if (g == 0) {
    marr[bh * cS + r0 + lr] = pm;    // log2-domain row max
    izarr[bh * cS + r0 + lr] = iz;
  }
  float wmax = wave_max(iz);
  if (lane == 0) atomicMax(maxiz_slot, __float_as_uint(wmax));
}

// ---------------- attention pass 2: P=u8-quant(softmax) ; ctx += P*V ----------------
// Swapped QK + per-lane softmax + packed b64 P-store + 1-iter software pipeline:
// iter kt: QK[kt]+store P[kt] (buf^1) ; PV of P[kt-64] (buf) with V[kt-64] regs;
// K[kt+64] and V[kt] register-prefetched. plds is wave-private; compiler handles lgkm.
__global__ __launch_bounds__(256) void attn_pass2_kernel(
    const unsigned short* __restrict__ qs, const unsigned short* __restrict__ ks,
    const unsigned short* __restrict__ vT, const float* __restrict__ marr,
    const float* __restrict__ izarr, float* __restrict__ ctx, const float* st,
    unsigned* amax_slot) {
  __shared__ __align__(16) unsigned short plds[4][2][16][88];  // stride 176B: b128-aligned, 2-way banks
  int bh = blockIdx.y, b = bh >> 3, h = bh & 7;
  int wid = threadIdx.x >> 6, lane = threadIdx.x & 63;
  int lr = lane & 15, g = lane >> 4, lk = g * 8;
  int r0 = blockIdx.x * 64 + wid * 16;
  float sscale2 = st[26], isa = st[21], cscale = st[22];
  v8bf aq0 = *(const v8bf*)(qs + ((size_t)bh * cS + r0 + lr) * cD + lk);
  v8bf aq1 = *(const v8bf*)(qs + ((size_t)bh * cS + r0 + lr) * cD + 32 + lk);
  float m2 = marr[bh * cS + r0 + lr];
  float fac = izarr[bh * cS + r0 + lr] * isa;
  const unsigned short* Kbase = ks + (size_t)bh * cS * cD;
  const unsigned short* Vbase = vT + (size_t)bh * cD * cS;

  v8bf K0[4], K1[4], V0[4], V1[4];
  f32x4 cacc[4] = {};

  auto loadK = [&](int kt) {
#pragma unroll
    for (int jc = 0; jc < 4; ++jc) {
      const unsigned short* p = Kbase + (size_t)(kt + jc * 16 + lr) * cD + lk;
      K0[jc] = *(const v8bf*)p; K1[jc] = *(const v8bf*)(p + 32);
    }
  };
  auto loadV = [&](int kt) {
#pragma unroll
    for (int dt = 0; dt < 4; ++dt) {
      const unsigned short* p = Vbase + (size_t)(dt * 16 + lr) * cS + kt + lk;
      V0[dt] = *(const v8bf*)p; V1[dt] = *(const v8bf*)(p + 32);
    }
  };
  // QK for tile kt (K regs already loaded) + softmax + packed P store into buffer bsel
  auto qk_store = [&](int bsel) {
#pragma unroll
    for (int jc = 0; jc < 4; ++jc) {
      f32x4 z = {0.f, 0.f, 0.f, 0.f};
      z = __builtin_amdgcn_mfma_f32_16x16x32_bf16(K0[jc], aq0, z, 0, 0, 0);
      z = __builtin_amdgcn_mfma_f32_16x16x32_bf16(K1[jc], aq1, z, 0, 0, 0);
      float a0 = fminf(rintf(__builtin_amdgcn_exp2f(__builtin_fmaf(z[0], sscale2, -m2)) * fac), 255.f);
      float a1 = fminf(rintf(__builtin_amdgcn_exp2f(__builtin_fmaf(z[1], sscale2, -m2)) * fac), 255.f);
      float a2 = fminf(rintf(__builtin_amdgcn_exp2f(__builtin_fmaf(z[2], sscale2, -m2)) * fac), 255.f);
      float a3 = fminf(rintf(__builtin_amdgcn_exp2f(__builtin_fmaf(z[3], sscale2, -m2)) * fac), 255.f);
      uint2 pw;
      pw.x = (__float_as_uint(a0) >> 16) | (__float_as_uint(a1) & 0xFFFF0000u);
      pw.y = (__float_as_uint(a2) >> 16) | (__float_as_uint(a3) & 0xFFFF0000u);
      *(uint2*)&plds[wid][bsel][lr][jc * 16 + g * 4] = pw;   // 4 consecutive k as one b64
    }
  };

  loadK(0);
  qk_store(0);
  loadK(64);
  loadV(0);
  int buf = 0;
  for (int kt = 64; kt < cS; kt += 64) {
    // PV for tile kt-64: P from plds[buf] (written last iter), V from regs
    v8bf ap0 = *(const v8bf*)&plds[wid][buf][lr][g * 8];
    v8bf ap1 = *(const v8bf*)&plds[wid][buf][lr][32 + g * 8];
#pragma unroll
    for (int dt = 0; dt < 4; ++dt) {
      cacc[dt] = __builtin_amdgcn_mfma_f32_16x16x32_bf16(ap0, V0[dt], cacc[dt], 0, 0, 0);
      cacc[dt] = __builtin_amdgcn_mfma_f32_16x16x32_bf16(ap1, V1[dt], cacc[dt], 0, 0, 0);
    }
    buf ^= 1;
    qk_store(buf);     // QK[kt] with K regs loaded last iter
    loadK(kt + 64);    // prefetch (last iter overshoots into vTb scratch — unused)
    loadV(kt);         // V for next iter's PV (WAR: V consumed above)
  }
  // epilogue: PV for the last tile
  {
    v8bf ap0 = *(const v8bf*)&plds[wid][buf][lr][g * 8];
    v8bf ap1 = *(const v8bf*)&plds[wid][buf][lr][32 + g * 8];
#pragma unroll
    for (int dt = 0; dt < 4; ++dt) {
      cacc[dt] = __builtin_amdgcn_mfma_f32_16x16x32_bf16(ap0, V0[dt], cacc[dt], 0, 0, 0);
      cacc[dt] = __builtin_amdgcn_mfma_f32_16x16x32_bf16(ap1, V1[dt], cacc[dt], 0, 0, 0);
    }
  }
  float lmax = 0.f;
#pragma unroll
  for (int dt = 0; dt < 4; ++dt)
#pragma unroll
    for (int r = 0; r < 4; ++r) {
      int qrow = r0 + g * 4 + r;
      int d = dt * 16 + lr;
      float val = cscale * cacc[dt][r];
      lmax = fmaxf(lmax, fabsf(val));
      ctx[((size_t)qrow * cB + b) * cE + h * cD + d] = val;  // [S][B][E]
    }
  lmax = wave_max(lmax);
  if (lane == 0) atomicMax(amax_slot, __float_as_uint(lmax));
}

// ---------------- launcher ----------------
extern "C" void kernel_launch(void* const* d_in, const int* in_sizes, int n_in, void* d_out,
                              int out_size, void* d_ws, size_t ws_size, hipStream_t stream) {
  (void)in_sizes; (void)n_in; (void)out_size; (void)ws_size;
  const float* x  = (const float*)d_in[0];
  const float* Wq = (const float*)d_in[1];
  const float* Wk = (const float*)d_in[2];
  const float* Wv = (const float*)d_in[3];
  const float* bq = (const float*)d_in[4];
  const float* bk = (const float*)d_in[5];
  const float* bv = (const float*)d_in[6];
  const float* Wo = (const float*)d_in[7];
  const float* bo = (const float*)d_in[8];
  float* out = (float*)d_out;

  char* ws = (char*)d_ws;
  size_t off = 0;
  auto alloc = [&](size_t bytes) { size_t o = off; off += (bytes + 255) & ~(size_t)255; return o; };
  float* st = (float*)(ws + alloc(64 * 4));
  unsigned short* xq  = (unsigned short*)(ws + alloc((size_t)cN * 2));
  unsigned short* wbq = (unsigned short*)(ws + alloc((size_t)cE * cE * 2));  // wbq..wbo contiguous
  unsigned short* wbk = (unsigned short*)(ws + alloc((size_t)cE * cE * 2));
  unsigned short* wbv = (unsigned short*)(ws + alloc((size_t)cE * cE * 2));
  unsigned short* wbo = (unsigned short*)(ws + alloc((size_t)cE * cE * 2));
  float* bfq = (float*)(ws + alloc(cE * 4));   // bfq..bfv contiguous
  float* bfk = (float*)(ws + alloc(cE * 4));
  float* bfv = (float*)(ws + alloc(cE * 4));
  float* bfo = (float*)(ws + alloc(cE * 4));
  float* qf = (float*)(ws + alloc((size_t)cN * 4));   // [BH][S][D]; qf,kf contiguous
  float* kf = (float*)(ws + alloc((size_t)cN * 4));
  float* vf = (float*)(ws + alloc((size_t)cN * 4));
  unsigned short* qsb = (unsigned short*)(ws + alloc((size_t)cN * 2));  // qsb,ksb contiguous
  unsigned short* ksb = (unsigned short*)(ws + alloc((size_t)cN * 2));
  unsigned short* vTb = (unsigned short*)(ws + alloc((size_t)cN * 2));
  float* marr  = (float*)(ws + alloc((size_t)cBH * cS * 4));
  float* izarr = (float*)(ws + alloc((size_t)cBH * cS * 4));
  float* ctxf = qf;                      // alias: qf dead after quant(q)
  unsigned short* cib = (unsigned short*)kf;  // alias: kf dead after quant(k)
  // total ws ~ 87 MB

  int n4 = cN / 4;
  int nw4 = cE * cE / 4;
  hipMemsetAsync(st, 0, 256, stream);
  absmax_kernel<<<1024, 256, 0, stream>>>(x, n4, (unsigned*)(st + 0));
  absmax4_kernel<<<dim3(64, 4), 256, 0, stream>>>(Wq, Wk, Wv, Wo, nw4, (unsigned*)(st + 1));
  scales_kernel<<<1, 1, 0, stream>>>(st, 0);
  quant_x_kernel<<<1024, 256, 0, stream>>>(x, xq, st, n4);
  quant_w4_kernel<<<dim3(64, 4), 256, 0, stream>>>(Wq, Wk, Wv, Wo, wbq, nw4, st);
  bias3_kernel<<<dim3(2, 3), 256, 0, stream>>>(bq, bk, bv, bfq, st);
  gemm_kernel<0><<<dim3(cSB / 64, cE / 64), 256, 0, stream>>>(xq, wbq, bfq, qf, st, 12, 13, (unsigned*)(st + 5));
  gemm_kernel<0><<<dim3(cSB / 64, cE / 64), 256, 0, stream>>>(xq, wbk, bfk, kf, st, 12, 14, (unsigned*)(st + 6));
  gemm_kernel<0><<<dim3(cSB / 64, cE / 64), 256, 0, stream>>>(xq, wbv, bfv, vf, st, 12, 15, (unsigned*)(st + 7));
  scales_kernel<<<1, 1, 0, stream>>>(st, 1);
  quant_qk_kernel<<<dim3(512, 2), 256, 0, stream>>>(qf, qsb, n4, st);
  quant_vT_kernel<<<dim3(cS / 64, cBH), 256, 0, stream>>>(vf, vTb, st);
  attn_pass1_kernel<<<dim3(cS / 64, cBH), 256, 0, stream>>>(qsb, ksb, marr, izarr, st, (unsigned*)(st + 8));
  scales_kernel<<<1, 1, 0, stream>>>(st, 2);
  attn_pass2_kernel<<<dim3(cS / 64, cBH), 256, 0, stream>>>(qsb, ksb, vTb, marr, izarr, ctxf, st, (unsigned*)(st + 9));
  scales_kernel<<<1, 1, 0, stream>>>(st, 3);
  quant_s8_kernel<<<1024, 256, 0, stream>>>(ctxf, cib, n4, st, 23, 1.0f);
  bias_kernel<<<2, 256, 0, stream>>>(bo, bfo, st, 23, 16);
  gemm_kernel<1><<<dim3(cSB / 64, cE / 64), 256, 0, stream>>>(cib, wbo, bfo, out, st, 23, 16, (unsigned*)(st + 10));
  scales_kernel<<<1, 1, 0, stream>>>(st, 4);
  final_quant_kernel<<<1024, 256, 0, stream>>>(out, st, n4);
}